// Round 8
// baseline (626.518 us; speedup 1.0000x reference)
//
#include <hip/hip_runtime.h>
#include <hip/hip_bf16.h>
#include <math.h>

#define D 64
#define NEG 0.2f
#define WPB 4
#define BLK 256
#define DPB 128
#define MAXNB 1024
#define CHUNK 16384
#define PCHUNK 8192
#define ECAP 4096          // max edges per 128-dst bucket (mean ~2046, sigma ~45)

typedef __attribute__((ext_vector_type(8))) short bf8;
typedef __attribute__((ext_vector_type(4))) float f4;
typedef __attribute__((ext_vector_type(4))) int i4;

#if defined(__has_builtin)
#  if __has_builtin(__builtin_amdgcn_fdot2_f32_bf16) && __has_builtin(__builtin_amdgcn_perm)
#    define HAS_BFDOT2 1
#  endif
#endif
#ifndef HAS_BFDOT2
#  define HAS_BFDOT2 0
#endif

#if HAS_BFDOT2
typedef __bf16 bfv2 __attribute__((ext_vector_type(2)));
#endif

__device__ __forceinline__ float lrelu(float v) { return v > 0.f ? v : NEG * v; }

__device__ __forceinline__ unsigned short f2bf(float f) {
    unsigned u = __float_as_uint(f);
    u = (u + 0x7fffu + ((u >> 16) & 1u)) >> 16;   // RTNE
    return (unsigned short)u;
}
__device__ __forceinline__ bf8 ld_frag_g(const unsigned short* p) {
    i4 v = *(const i4*)p;
    return __builtin_bit_cast(bf8, v);
}

__device__ __forceinline__ const int* edge_ptr(const int* e0, const int* e1,
                                               const int* e2, const int* e3, int r)
{
    return (r == 0) ? e0 : (r == 1) ? e1 : (r == 2) ? e2 : e3;
}

// ---------------- bucketed CSR build ----------------

__global__ __launch_bounds__(256) void k_bcount(
    const int* __restrict__ e0, const int* __restrict__ e1,
    const int* __restrict__ e2, const int* __restrict__ e3,
    int* __restrict__ bcnt, int E, int NB)
{
    int r = blockIdx.y;
    const int* dst = edge_ptr(e0, e1, e2, e3, r) + E;
    __shared__ int hist[MAXNB];
    for (int i = threadIdx.x; i < NB; i += 256) hist[i] = 0;
    __syncthreads();
    int base = blockIdx.x * CHUNK;
    int end = base + CHUNK < E ? base + CHUNK : E;
    for (int i = base + threadIdx.x; i < end; i += 256)
        atomicAdd(&hist[dst[i] >> 7], 1);
    __syncthreads();
    for (int i = threadIdx.x; i < NB; i += 256)
        if (hist[i]) atomicAdd(&bcnt[r * NB + i], hist[i]);
}

__global__ __launch_bounds__(1024) void k_bscan(
    const int* __restrict__ bcnt, int* __restrict__ boff,
    int* __restrict__ bcur, int E, int NB)
{
    int r = blockIdx.y;
    __shared__ int sh[1024];
    int t = threadIdx.x;
    int v = (t < NB) ? bcnt[r * NB + t] : 0;
    sh[t] = v;
    __syncthreads();
    for (int off = 1; off < 1024; off <<= 1) {
        int add = (t >= off) ? sh[t - off] : 0;
        __syncthreads();
        sh[t] += add;
        __syncthreads();
    }
    if (t < NB) {
        int excl = sh[t] - v;
        boff[r * (NB + 1) + t] = excl;
        bcur[r * NB + t] = excl;
    }
    if (t == 0) boff[r * (NB + 1) + NB] = E;
}

// LDS counting-sort partition -> bucket-grouped packed edges (src<<7 | d&127)
__global__ __launch_bounds__(256) void k_part(
    const int* __restrict__ e0, const int* __restrict__ e1,
    const int* __restrict__ e2, const int* __restrict__ e3,
    int* __restrict__ gcur, unsigned* __restrict__ edges, int E, int NB)
{
    __shared__ unsigned vals[PCHUNK];
    __shared__ unsigned short bkt[PCHUNK];
    __shared__ int hist[MAXNB];
    __shared__ int sbase[MAXNB];
    __shared__ int gdelta[MAXNB];
    __shared__ int ssum[256];
    int r = blockIdx.y;
    const int* ep = edge_ptr(e0, e1, e2, e3, r);
    const int* srcp = ep;
    const int* dstp = ep + E;
    int t = threadIdx.x;
    for (int j = t; j < MAXNB; j += 256) hist[j] = 0;
    __syncthreads();
    int begin = blockIdx.x * PCHUNK;
    int end = begin + PCHUNK < E ? begin + PCHUNK : E;
    int cnt = end - begin;
    for (int i = begin + t; i < end; i += 256)
        atomicAdd(&hist[dstp[i] >> 7], 1);
    __syncthreads();
    int h0 = hist[t * 4], h1 = hist[t * 4 + 1], h2 = hist[t * 4 + 2], h3 = hist[t * 4 + 3];
    int lsum = h0 + h1 + h2 + h3;
    ssum[t] = lsum;
    __syncthreads();
    for (int off = 1; off < 256; off <<= 1) {
        int a = (t >= off) ? ssum[t - off] : 0;
        __syncthreads();
        ssum[t] += a;
        __syncthreads();
    }
    int ex = ssum[t] - lsum;
    sbase[t * 4] = ex;
    sbase[t * 4 + 1] = ex + h0;
    sbase[t * 4 + 2] = ex + h0 + h1;
    sbase[t * 4 + 3] = ex + h0 + h1 + h2;
    __syncthreads();
    for (int j = t; j < NB; j += 256) {
        int c = hist[j];
        int gb = c ? atomicAdd(&gcur[r * NB + j], c) : 0;
        gdelta[j] = gb - sbase[j];
    }
    __syncthreads();
    for (int j = t; j < MAXNB; j += 256) hist[j] = 0;
    __syncthreads();
    for (int i = begin + t; i < end; i += 256) {
        int d = dstp[i];
        int s = srcp[i];
        int b = d >> 7;
        int rank = atomicAdd(&hist[b], 1);
        int p = sbase[b] + rank;
        vals[p] = ((unsigned)s << 7) | (unsigned)(d & 127);
        bkt[p] = (unsigned short)b;
    }
    __syncthreads();
    unsigned* stg = edges + (size_t)r * E;
    for (int p = t; p < cnt; p += 256)
        stg[p + gdelta[bkt[p]]] = vals[p];
}

// ---------------- setup: cast + weight packing ----------------

__global__ __launch_bounds__(256) void k_xcast(
    const float* __restrict__ x, unsigned short* __restrict__ xb, int n4)
{
    int i = blockIdx.x * 256 + threadIdx.x;
    if (i < n4) {
        float4 v = ((const float4*)x)[i];
        ushort4 o;
        o.x = f2bf(v.x); o.y = f2bf(v.y); o.z = f2bf(v.z); o.w = f2bf(v.w);
        ((ushort4*)xb)[i] = o;
    }
}

__global__ __launch_bounds__(64) void k_pack(
    const float* __restrict__ gatW, const float* __restrict__ atS,
    const float* __restrict__ atD, const float* __restrict__ W1,
    const float* __restrict__ W2, unsigned short* __restrict__ WgP,
    unsigned short* __restrict__ W1P, unsigned short* __restrict__ W2P)
{
    int f = blockIdx.x;
    int L = threadIdx.x;
    int kg = L >> 4, c = L & 15;
    unsigned short vals[8];
    unsigned short* dst;
    if (f < 80) {
        int m = f / 10, rem = f % 10;
        int l = m / 4, r = m % 4;
        int kc = rem / 5, ct = rem % 5;
        const float* W = gatW + (size_t)(l * 4 + r) * D * D;
        if (ct < 4) {
#pragma unroll
            for (int j = 0; j < 8; j++) {
                int k = kc * 32 + kg * 8 + j;
                vals[j] = f2bf(W[k * D + ct * 16 + c]);
            }
        } else {
            const float* att = (c == 0) ? atS + (size_t)(l * 4 + r) * D
                                        : atD + (size_t)(l * 4 + r) * D;
#pragma unroll
            for (int j = 0; j < 8; j++) {
                int k = kc * 32 + kg * 8 + j;
                float s = 0.f;
                if (c < 2)
                    for (int cc = 0; cc < D; cc++) s += W[k * D + cc] * att[cc];
                vals[j] = f2bf(s);
            }
        }
        dst = WgP + ((size_t)f * 64 + L) * 8;
    } else if (f < 160) {
        int f2 = f - 80;
        int l = f2 / 40, rem = f2 % 40;
        int kc = rem / 4, ct = rem % 4;
        const float* W = W1 + (size_t)l * 5 * D * D;
#pragma unroll
        for (int j = 0; j < 8; j++) {
            int k = kc * 32 + kg * 8 + j;
            vals[j] = f2bf(W[k * D + ct * 16 + c]);
        }
        dst = W1P + ((size_t)f2 * 64 + L) * 8;
    } else {
        int f3 = f - 160;
        int l = f3 / 8, rem = f3 % 8;
        int kc = rem / 4, ct = rem % 4;
        const float* W = W2 + (size_t)l * D * D;
#pragma unroll
        for (int j = 0; j < 8; j++) {
            int k = kc * 32 + kg * 8 + j;
            vals[j] = f2bf(W[k * D + ct * 16 + c]);
        }
        dst = W2P + ((size_t)f3 * 64 + L) * 8;
    }
    i4 v = __builtin_bit_cast(i4, *(bf8*)vals);
    *(i4*)dst = v;
}

// ---------------- MFMA compute ----------------

__device__ __forceinline__ void gemm_h_body(
    bf8 a0, bf8 a1, const unsigned short* __restrict__ WgPl,
    unsigned short* __restrict__ h, float* __restrict__ a_s,
    float* __restrict__ a_d, int n0, int kg, int lo, int L, int N)
{
#pragma unroll
    for (int r = 0; r < 4; r++) {
        const unsigned short* Wbase = WgPl + (size_t)r * 10 * 512;
#pragma unroll
        for (int ct = 0; ct < 5; ct++) {
            f4 acc = {0.f, 0.f, 0.f, 0.f};
            bf8 b0 = ld_frag_g(Wbase + (size_t)ct * 512 + (size_t)L * 8);
            bf8 b1 = ld_frag_g(Wbase + (size_t)(5 + ct) * 512 + (size_t)L * 8);
            acc = __builtin_amdgcn_mfma_f32_16x16x32_bf16(a0, b0, acc, 0, 0, 0);
            acc = __builtin_amdgcn_mfma_f32_16x16x32_bf16(a1, b1, acc, 0, 0, 0);
#pragma unroll
            for (int q = 0; q < 4; q++) {
                int node = n0 + kg * 4 + q;
                if (node < N) {
                    if (ct < 4)
                        h[((size_t)r * N + node) * D + ct * 16 + lo] = f2bf(acc[q]);
                    else if (lo == 0)
                        a_s[(size_t)r * N + node] = acc[q];
                    else if (lo == 1)
                        a_d[(size_t)r * N + node] = acc[q];
                }
            }
        }
    }
}

__global__ __launch_bounds__(BLK) void k_gemm_h(
    const unsigned short* __restrict__ xb, const unsigned short* __restrict__ WgPl,
    unsigned short* __restrict__ h, float* __restrict__ a_s,
    float* __restrict__ a_d, int N)
{
    int w = threadIdx.x >> 6, L = threadIdx.x & 63;
    int n0 = blockIdx.x * 64 + w * 16;
    int lo = L & 15, kg = L >> 4;
    int nA = n0 + lo; if (nA >= N) nA = N - 1;
    bf8 a0 = ld_frag_g(xb + (size_t)nA * D + kg * 8);
    bf8 a1 = ld_frag_g(xb + (size_t)nA * D + 32 + kg * 8);
    gemm_h_body(a0, a1, WgPl, h, a_s, a_d, n0, kg, lo, L, N);
}

// GAT aggregation: one block per (128-dst bucket, relation).
// Phase 1: in-LDS counting sort of the bucket's edges (replaces k_place).
// Phase 2: each wave processes 32 dsts as 16 pairs (2 dsts/wave-pass);
// inner loop uses int4 (off0,off1,epk) staging + v_dot2_f32_bf16 when available.
__global__ __launch_bounds__(BLK) void k_agg(
    const unsigned short* __restrict__ h, const float* __restrict__ a_sall,
    const float* __restrict__ a_dall, const int* __restrict__ boff,
    const unsigned* __restrict__ edges, const float* __restrict__ gatB,
    unsigned short* __restrict__ g, int N, int E, int NB)
{
    __shared__ int sorted[ECAP];
    __shared__ int lcount[DPB];
    __shared__ int lstart[DPB];
    __shared__ int lcur[DPB];
    __shared__ float adst[DPB];
    __shared__ i4 comb[WPB][32];     // [wave][half*16 + q]
    int r = blockIdx.y;
    int bktb = blockIdx.x;
    int t = threadIdx.x;
    int w = t >> 6, lane = t & 63;
    int half = lane >> 5, fl = lane & 31;
    int d0 = bktb * DPB;

    const unsigned short* hr = h + (size_t)r * N * D;
    const float* asr = a_sall + (size_t)r * N;

    int base = boff[r * (NB + 1) + bktb];
    int cnt  = boff[r * (NB + 1) + bktb + 1] - base;
    const unsigned* eb = edges + (size_t)r * E + base;

    if (t < DPB) {
        lcount[t] = 0;
        int dd = d0 + t;
        adst[t] = (dd < N) ? a_dall[(size_t)r * N + dd] : 0.f;
    }
    __syncthreads();
    for (int i = t; i < cnt; i += 256)
        atomicAdd(&lcount[eb[i] & 127], 1);
    __syncthreads();
    if (t < DPB) lstart[t] = lcount[t];
    __syncthreads();
    for (int off = 1; off < DPB; off <<= 1) {
        int add = (t < DPB && t >= off) ? lstart[t - off] : 0;
        __syncthreads();
        if (t < DPB) lstart[t] += add;
        __syncthreads();
    }
    if (t < DPB) {
        int excl = lstart[t] - lcount[t];
        lstart[t] = excl;
        lcur[t] = excl;
    }
    __syncthreads();
    for (int i = t; i < cnt; i += 256) {
        unsigned v = eb[i];                       // L2-hot re-read
        int pos = atomicAdd(&lcur[v & 127], 1);
        sorted[pos] = (int)(v >> 7);
    }
    __syncthreads();

    const float gb0 = gatB[r * D + 2 * fl];
    const float gb1 = gatB[r * D + 2 * fl + 1];

    for (int p = 0; p < 16; p++) {
        int dl = w * 32 + p * 2 + half;           // local dst 0..127
        int d  = d0 + dl;
        bool real = d < N;
        int dd = real ? d : d0;                   // clamp for gathers
        int cd = lcount[dl];
        int st = lstart[dl];
        float ad = adst[dl];

        float e_self = __expf(lrelu(asr[dd] + ad));
        float zpart = (fl == 0) ? e_self : 0.f;
        float accx, accy;
        {
            unsigned u = ((const unsigned*)(hr + (size_t)dd * D))[fl];
            accx = e_self * __uint_as_float(u << 16);
            accy = e_self * __uint_as_float(u & 0xffff0000u);
        }

        int cmax = max(cd, __shfl_xor(cd, 32));
        for (int c0 = 0; c0 < cmax; c0 += 32) {
            int jj = c0 + fl;
            bool valid = jj < cd;
            int src = valid ? sorted[st + jj] : 0;
            float e = valid ? __expf(lrelu(asr[src] + ad)) : 0.f;
            zpart += e;
            int q = fl >> 1;
            ((int*)&comb[w][half * 16 + q])[fl & 1] = src * (int)(D * 2);
            float eo = __shfl_down(e, 1);
            if ((fl & 1) == 0) {
                unsigned pk = (unsigned)f2bf(e) | ((unsigned)f2bf(eo) << 16);
                ((int*)&comb[w][half * 16 + q])[2] = (int)pk;
            }
            __threadfence_block();
            int lim = cmax - c0; if (lim > 32) lim = 32;
            int steps = (lim + 1) >> 1;
#pragma unroll 4
            for (int s = 0; s < steps; s++) {
                i4 pv = comb[w][half * 16 + s];
                unsigned uA = *(const unsigned*)((const char*)hr + pv.x + fl * 4);
                unsigned uB = *(const unsigned*)((const char*)hr + pv.y + fl * 4);
#if HAS_BFDOT2
                unsigned lopk = __builtin_amdgcn_perm(uB, uA, 0x05040100u);
                unsigned hipk = __builtin_amdgcn_perm(uB, uA, 0x07060302u);
                bfv2 ep2 = __builtin_bit_cast(bfv2, (unsigned)pv.z);
                accx = __builtin_amdgcn_fdot2_f32_bf16(
                    __builtin_bit_cast(bfv2, lopk), ep2, accx, false);
                accy = __builtin_amdgcn_fdot2_f32_bf16(
                    __builtin_bit_cast(bfv2, hipk), ep2, accy, false);
#else
                float eA = __uint_as_float(((unsigned)pv.z) << 16);
                float eB = __uint_as_float(((unsigned)pv.z) & 0xffff0000u);
                accx = fmaf(eA, __uint_as_float(uA << 16), accx);
                accy = fmaf(eA, __uint_as_float(uA & 0xffff0000u), accy);
                accx = fmaf(eB, __uint_as_float(uB << 16), accx);
                accy = fmaf(eB, __uint_as_float(uB & 0xffff0000u), accy);
#endif
            }
            __threadfence_block();
        }

        float z = zpart;
#pragma unroll
        for (int off = 16; off; off >>= 1) z += __shfl_xor(z, off);

        if (real) {
            float rz = 1.f / z;
            float vlo = accx * rz + gb0;
            float vhi = accy * rz + gb1;
            unsigned o = (unsigned)f2bf(vlo) | ((unsigned)f2bf(vhi) << 16);
            ((unsigned*)g)[((size_t)r * N + d) * 32 + fl] = o;
        }
    }
}

// fused MLP (+ next-layer gemm_h when !last)
__global__ __launch_bounds__(BLK) void k_mlp(
    const unsigned short* __restrict__ xb, const unsigned short* __restrict__ g,
    const unsigned short* __restrict__ W1Pl, const float* __restrict__ b1l,
    const unsigned short* __restrict__ W2Pl, const float* __restrict__ b2l,
    void* __restrict__ outp, int N, int last,
    const unsigned short* __restrict__ WgPn, unsigned short* __restrict__ hn,
    float* __restrict__ a_sn, float* __restrict__ a_dn)
{
    __shared__ unsigned short sh[WPB][16 * 80];
    int w = threadIdx.x >> 6, L = threadIdx.x & 63;
    int n0 = blockIdx.x * 64 + w * 16;
    int lo = L & 15, kg = L >> 4;
    int nA = n0 + lo; if (nA >= N) nA = N - 1;

    f4 acc[4];
#pragma unroll
    for (int ct = 0; ct < 4; ct++) acc[ct] = (f4){0.f, 0.f, 0.f, 0.f};

#pragma unroll
    for (int p = 0; p < 5; p++) {
        const unsigned short* plane = (p == 0) ? xb : g + (size_t)(p - 1) * N * D;
#pragma unroll
        for (int kc2 = 0; kc2 < 2; kc2++) {
            bf8 a = ld_frag_g(plane + (size_t)nA * D + kc2 * 32 + kg * 8);
            int kc = p * 2 + kc2;
#pragma unroll
            for (int ct = 0; ct < 4; ct++) {
                bf8 b = ld_frag_g(W1Pl + ((size_t)(kc * 4 + ct) * 512 + (size_t)L * 8));
                acc[ct] = __builtin_amdgcn_mfma_f32_16x16x32_bf16(a, b, acc[ct], 0, 0, 0);
            }
        }
    }

    unsigned short* tile = &sh[w][0];
#pragma unroll
    for (int ct = 0; ct < 4; ct++) {
        float bb = b1l[ct * 16 + lo];
#pragma unroll
        for (int q = 0; q < 4; q++)
            tile[(kg * 4 + q) * 80 + ct * 16 + lo] = f2bf(tanhf(acc[ct][q] + bb));
    }
    __syncthreads();

    f4 o[4];
#pragma unroll
    for (int ct = 0; ct < 4; ct++) o[ct] = (f4){0.f, 0.f, 0.f, 0.f};
#pragma unroll
    for (int kc = 0; kc < 2; kc++) {
        const unsigned short* ap = tile + lo * 80 + kc * 32 + kg * 8;
        i4 av = *(const i4*)ap;
        bf8 a = __builtin_bit_cast(bf8, av);
#pragma unroll
        for (int ct = 0; ct < 4; ct++) {
            bf8 b = ld_frag_g(W2Pl + ((size_t)(kc * 4 + ct) * 512 + (size_t)L * 8));
            o[ct] = __builtin_amdgcn_mfma_f32_16x16x32_bf16(a, b, o[ct], 0, 0, 0);
        }
    }
    __syncthreads();
#pragma unroll
    for (int ct = 0; ct < 4; ct++) {
        float bb = b2l[ct * 16 + lo];
#pragma unroll
        for (int q = 0; q < 4; q++) {
            int node = n0 + kg * 4 + q;
            int col = ct * 16 + lo;
            float v = o[ct][q] + bb;
            if (node < N) {
                if (last) ((float*)outp)[(size_t)node * D + col] = v;
                else ((unsigned short*)outp)[(size_t)node * D + col] = f2bf(v);
            }
            if (!last) tile[(kg * 4 + q) * 80 + col] = f2bf(v);
        }
    }
    if (last) return;

    __syncthreads();
    bf8 a0, a1;
    {
        i4 v0 = *(const i4*)(tile + lo * 80 + kg * 8);
        i4 v1 = *(const i4*)(tile + lo * 80 + 32 + kg * 8);
        a0 = __builtin_bit_cast(bf8, v0);
        a1 = __builtin_bit_cast(bf8, v1);
    }
    gemm_h_body(a0, a1, WgPn, hn, a_sn, a_dn, n0, kg, lo, L, N);
}

// ---------------- launch ----------------

extern "C" void kernel_launch(void* const* d_in, const int* in_sizes, int n_in,
                              void* d_out, int out_size, void* d_ws, size_t ws_size,
                              hipStream_t stream)
{
    const float* x    = (const float*)d_in[0];
    const int*   e0   = (const int*)d_in[1];
    const int*   e1   = (const int*)d_in[2];
    const int*   e2   = (const int*)d_in[3];
    const int*   e3   = (const int*)d_in[4];
    const float* gatW = (const float*)d_in[5];
    const float* atS  = (const float*)d_in[6];
    const float* atD  = (const float*)d_in[7];
    const float* gatB = (const float*)d_in[8];
    const float* W1   = (const float*)d_in[9];
    const float* b1   = (const float*)d_in[10];
    const float* W2   = (const float*)d_in[11];
    const float* b2   = (const float*)d_in[12];
    float* out = (float*)d_out;

    const int N = in_sizes[0] / D;
    const int E = in_sizes[1] / 2;
    const int NB = (N + DPB - 1) / DPB;

    size_t off = 0;
    auto alloc = [&](size_t bytes) { size_t o = off; off = (off + bytes + 255) & ~(size_t)255; return o; };
    unsigned short* xb    = (unsigned short*)((char*)d_ws + alloc((size_t)N * D * 2));
    unsigned short* xnext = (unsigned short*)((char*)d_ws + alloc((size_t)N * D * 2));
    unsigned short* h     = (unsigned short*)((char*)d_ws + alloc((size_t)4 * N * D * 2));
    unsigned short* g     = (unsigned short*)((char*)d_ws + alloc((size_t)4 * N * D * 2));
    unsigned* edges = (unsigned*)((char*)d_ws + alloc((size_t)4 * E * 4));
    float* a_s   = (float*)((char*)d_ws + alloc((size_t)4 * N * 4));
    float* a_d   = (float*)((char*)d_ws + alloc((size_t)4 * N * 4));
    int* bcnt    = (int*)((char*)d_ws + alloc((size_t)4 * NB * 4));
    int* boff    = (int*)((char*)d_ws + alloc((size_t)4 * (NB + 1) * 4));
    int* bcur    = (int*)((char*)d_ws + alloc((size_t)4 * NB * 4));
    unsigned short* WgP = (unsigned short*)((char*)d_ws + alloc((size_t)80 * 512 * 2));
    unsigned short* W1P = (unsigned short*)((char*)d_ws + alloc((size_t)80 * 512 * 2));
    unsigned short* W2P = (unsigned short*)((char*)d_ws + alloc((size_t)16 * 512 * 2));
    (void)ws_size;

    const int cntBlocks  = (E + CHUNK - 1) / CHUNK;
    const int partBlocks = (E + PCHUNK - 1) / PCHUNK;
    const int tileBlocks = (N + 63) / 64;

    k_pack<<<176, 64, 0, stream>>>(gatW, atS, atD, W1, W2, WgP, W1P, W2P);
    k_xcast<<<(N * D / 4 + 255) / 256, 256, 0, stream>>>(x, xb, N * D / 4);

    hipMemsetAsync(bcnt, 0, (size_t)4 * NB * 4, stream);
    k_bcount<<<dim3(cntBlocks, 4), 256, 0, stream>>>(e0, e1, e2, e3, bcnt, E, NB);
    k_bscan<<<dim3(1, 4), 1024, 0, stream>>>(bcnt, boff, bcur, E, NB);
    k_part<<<dim3(partBlocks, 4), 256, 0, stream>>>(e0, e1, e2, e3, bcur, edges, E, NB);

    // layer 0
    k_gemm_h<<<tileBlocks, BLK, 0, stream>>>(xb, WgP, h, a_s, a_d, N);
    k_agg<<<dim3(NB, 4), BLK, 0, stream>>>(
        h, a_s, a_d, boff, edges, gatB, g, N, E, NB);
    k_mlp<<<tileBlocks, BLK, 0, stream>>>(
        xb, g, W1P, b1, W2P, b2, xnext, N, 0,
        WgP + (size_t)40 * 512, h, a_s, a_d);   // fused layer-1 gemm_h

    // layer 1
    k_agg<<<dim3(NB, 4), BLK, 0, stream>>>(
        h, a_s, a_d, boff, edges, gatB + (size_t)4 * D, g, N, E, NB);
    k_mlp<<<tileBlocks, BLK, 0, stream>>>(
        xnext, g, W1P + (size_t)40 * 512, b1 + D, W2P + (size_t)8 * 512, b2 + D,
        out, N, 1, nullptr, nullptr, nullptr, nullptr);
}